// Round 9
// baseline (182.139 us; speedup 1.0000x reference)
//
#include <hip/hip_runtime.h>
#include <math.h>

// Analytic inverse of [[R, t],[0,0,0,1]] where R comes from a normalized quat:
// inv = [[R^T, -R^T t],[0,0,0,1]].
struct Inv {
    float i00, i01, i02, it0;
    float i10, i11, i12, it1;
    float i20, i21, i22, it2;
};

__device__ __forceinline__ Inv make_inv(const float* __restrict__ q,
                                        const float* __restrict__ t, int b) {
    float w = q[b * 4 + 0], x = q[b * 4 + 1], y = q[b * 4 + 2], z = q[b * 4 + 3];
    float inv_n = 1.0f / sqrtf(w * w + x * x + y * y + z * z);
    w *= inv_n; x *= inv_n; y *= inv_n; z *= inv_n;
    float R00 = 1.f - 2.f * y * y - 2.f * z * z;
    float R01 = 2.f * x * y - 2.f * z * w;
    float R02 = 2.f * x * z + 2.f * y * w;
    float R10 = 2.f * x * y + 2.f * z * w;
    float R11 = 1.f - 2.f * x * x - 2.f * z * z;
    float R12 = 2.f * y * z - 2.f * x * w;
    float R20 = 2.f * x * z - 2.f * y * w;
    float R21 = 2.f * y * z + 2.f * x * w;
    float R22 = 1.f - 2.f * x * x - 2.f * y * y;
    float t0 = t[b * 3 + 0], t1 = t[b * 3 + 1], t2 = t[b * 3 + 2];
    Inv v;
    v.i00 = R00; v.i01 = R10; v.i02 = R20; v.it0 = -(R00 * t0 + R10 * t1 + R20 * t2);
    v.i10 = R01; v.i11 = R11; v.i12 = R21; v.it1 = -(R01 * t0 + R11 * t1 + R21 * t2);
    v.i20 = R02; v.i21 = R12; v.i22 = R22; v.it2 = -(R02 * t0 + R12 * t1 + R22 * t2);
    return v;
}

__device__ __forceinline__ void xf(const Inv& M, float px, float py, float pz,
                                   float& ox, float& oy, float& oz) {
    ox = fmaf(M.i00, px, fmaf(M.i01, py, fmaf(M.i02, pz, M.it0)));
    oy = fmaf(M.i10, px, fmaf(M.i11, py, fmaf(M.i12, pz, M.it1)));
    oz = fmaf(M.i20, px, fmaf(M.i21, py, fmaf(M.i22, pz, M.it2)));
}

using nat_f4 = __attribute__((ext_vector_type(4))) float;
// NT load — KEPT (R6: the only knob that ever moved the needle, −5 us;
// bypasses L3 retention -> clean full HBM read stream).
__device__ __forceinline__ float4 load_nt(const float4* p) {
    nat_f4 v = __builtin_nontemporal_load((const nat_f4*)p);
    float4 r; *(nat_f4*)&r = v; return r;
}

// ROUND 9 — read-concurrency probe (ILP=4). Experiment matrix so far:
// {LDS+barriers, persistent+counted-vmcnt, zero-sync streaming} x
// {cached,NT loads} x {cached,NT stores} factorizes: NT loads −5 us, store
// policy 0, schedule 0. Kernel pinned at ~55 us = 3.5 TB/s combined while
// the in-harness fill does 6.7 TB/s writes in identical windows -> the READ
// stream runs at only ~2.4 TB/s. Candidate limiter: HBM latency (~900 cy) x
// finite outstanding reads. R1 (~3 in flight/wave) tied R8 (1 in flight),
// but the knee may sit above 3. This kernel issues 4 independent NT loads
// per thread before ANY consumption (4x in-flight bytes/wave, ~128 KB/CU
// outstanding at full occupancy). If flat again -> reads are HW-capped
// (MSHR/controller) and ~55 us is the documented roofline.
//
// Geometry: block tile = 1024 float4; thread j-th slice w_j = tile + j*256
// + tid (all coalesced). f4_per_batch = 196608 = 192*1024 -> every tile
// lies in ONE batch; 196608 % 3 == 0 -> each batch starts at phase 0, so
// cross-batch neighbor words are never consumed (verified: R8 passed with
// identical absmax). Neighbor words via delta-1 lane shuffles + masked
// wave-edge fixup loads, as in R8.
__global__ __launch_bounds__(256) void realign_ilp4_kernel(
        const float4* __restrict__ pcd,
        const float* __restrict__ T_mis,
        const float* __restrict__ q,
        const float* __restrict__ t,
        float* __restrict__ out_mat,
        float4* __restrict__ out_pcd,
        int f4_per_batch, int total_f4) {
    const int tid  = threadIdx.x;
    const int lane = tid & 63;
    const int tile = blockIdx.x << 10;          // 1024 float4 per block

    int w[4];
    float4 A[4];
    // Phase 1: issue ALL FOUR independent NT loads back-to-back.
    #pragma unroll
    for (int j = 0; j < 4; ++j) {
        w[j] = tile + (j << 8) + tid;
        A[j] = load_nt(&pcd[w[j]]);
    }

    // Batch is block-uniform (tile size divides f4_per_batch).
    const int b = tile / f4_per_batch;
    const Inv M = make_inv(q, t, b);

    // Fused tmat: batch_T_pred = inv_T @ T_mis (512 elems, block 0 only).
    if (blockIdx.x == 0 && tid < 512) {
        // j=0 slice covers w=0..255, j=1 covers 256..511; do it directly
        // from tid over two elements to keep it simple and uniform.
        #pragma unroll
        for (int e = 0; e < 2; ++e) {
            const int we = (e << 8) + tid;
            const int bb = we >> 4;
            const int i  = (we >> 2) & 3;
            const int jj = we & 3;
            const Inv Mb = make_inv(q, t, bb);
            const float* Tb = T_mis + bb * 16;
            float val;
            if (i < 3) {
                float a0, a1, a2, itr;
                if (i == 0)      { a0 = Mb.i00; a1 = Mb.i01; a2 = Mb.i02; itr = Mb.it0; }
                else if (i == 1) { a0 = Mb.i10; a1 = Mb.i11; a2 = Mb.i12; itr = Mb.it1; }
                else             { a0 = Mb.i20; a1 = Mb.i21; a2 = Mb.i22; itr = Mb.it2; }
                val = fmaf(a0, Tb[0 * 4 + jj],
                      fmaf(a1, Tb[1 * 4 + jj],
                      fmaf(a2, Tb[2 * 4 + jj],
                           itr * Tb[3 * 4 + jj])));
            } else {
                val = Tb[3 * 4 + jj];
            }
            out_mat[we] = val;
        }
    }

    const float* pf = (const float*)pcd;
    float4 o[4];

    // Phase 2: per slice — shuffles, edge fixups, 12 FMAs.
    #pragma unroll
    for (int j = 0; j < 4; ++j) {
        float lom2 = __shfl_up(A[j].z, 1);
        float lom1 = __shfl_up(A[j].w, 1);
        float hi4  = __shfl_down(A[j].x, 1);
        float hi5  = __shfl_down(A[j].y, 1);
        if (lane == 0 && w[j] > 0) {
            lom2 = pf[4 * w[j] - 2];
            lom1 = pf[4 * w[j] - 1];
        }
        if (lane == 63 && w[j] + 1 < total_f4) {
            hi4 = pf[4 * w[j] + 4];
            hi5 = pf[4 * w[j] + 5];
        }
        const int phi = w[j] % 3;
        if (phi == 0) {
            xf(M, A[j].x, A[j].y, A[j].z, o[j].x, o[j].y, o[j].z);
            o[j].w = fmaf(M.i00, A[j].w, fmaf(M.i01, hi4, fmaf(M.i02, hi5, M.it0)));
        } else if (phi == 1) {
            o[j].x = fmaf(M.i10, lom1, fmaf(M.i11, A[j].x, fmaf(M.i12, A[j].y, M.it1)));
            o[j].y = fmaf(M.i20, lom1, fmaf(M.i21, A[j].x, fmaf(M.i22, A[j].y, M.it2)));
            o[j].z = fmaf(M.i00, A[j].z, fmaf(M.i01, A[j].w, fmaf(M.i02, hi4, M.it0)));
            o[j].w = fmaf(M.i10, A[j].z, fmaf(M.i11, A[j].w, fmaf(M.i12, hi4, M.it1)));
        } else {
            o[j].x = fmaf(M.i20, lom2, fmaf(M.i21, lom1, fmaf(M.i22, A[j].x, M.it2)));
            xf(M, A[j].y, A[j].z, A[j].w, o[j].y, o[j].z, o[j].w);
        }
    }

    // Phase 3: 4 coalesced stores (cached — policy proven neutral R4/R7).
    #pragma unroll
    for (int j = 0; j < 4; ++j) {
        out_pcd[w[j]] = o[j];
    }
}

extern "C" void kernel_launch(void* const* d_in, const int* in_sizes, int n_in,
                              void* d_out, int out_size, void* d_ws, size_t ws_size,
                              hipStream_t stream) {
    const float* pcd   = (const float*)d_in[0];  // (B, N, 3)
    const float* T_mis = (const float*)d_in[1];  // (B, 4, 4)
    const float* q     = (const float*)d_in[2];  // (B, 4)
    const float* t     = (const float*)d_in[3];  // (B, 3)
    float* out = (float*)d_out;

    const int B = in_sizes[2] / 4;                            // 32
    const long long N = (long long)in_sizes[0] / (3LL * B);   // 262144
    const int f4_per_batch = (int)(3 * N / 4);                // 196608 (=192*1024)
    const int total_f4 = f4_per_batch * B;                    // 6291456
    const int blocks = total_f4 / 1024;                       // 6144 (exact)

    // Output layout: [0, B*16) = batch_T_pred; then pcd_new (float4-aligned).
    realign_ilp4_kernel<<<dim3(blocks), 256, 0, stream>>>(
        (const float4*)pcd, T_mis, q, t,
        out, (float4*)(out + B * 16), f4_per_batch, total_f4);
}

// Round 10
// 174.858 us; speedup vs baseline: 1.0416x; 1.0416x over previous
//
#include <hip/hip_runtime.h>
#include <math.h>

// FINAL CONFIGURATION (restored R7 — best measured total, 174.2 us).
//
// Closed experiment matrix (R0-R9): schedule {LDS+barriers, persistent
// counted-vmcnt, zero-sync streaming, ILP=4} x load {cached, NT} x store
// {cached, NT} x read-concurrency {1,3,4}: every axis null EXCEPT NT loads
// (−5 us). Kernel pinned at ~54-56 us = 3.5 TB/s combined on 194 MB
// irreducible fp32 traffic, while the in-harness fill sustains 6.7 TB/s
// writes in identical windows. Binding constraint: cold HBM reads (~2.4
// TB/s effective) under harness-enforced cache turnover (2 x 403 MB fills
// per replay flush L2/L3 before every kernel run). Schedule-independent,
// concurrency-independent -> memory-system roofline for this stream mix.

// Analytic inverse of [[R, t],[0,0,0,1]] where R comes from a normalized quat:
// inv = [[R^T, -R^T t],[0,0,0,1]].
struct Inv {
    float i00, i01, i02, it0;
    float i10, i11, i12, it1;
    float i20, i21, i22, it2;
};

__device__ __forceinline__ Inv make_inv(const float* __restrict__ q,
                                        const float* __restrict__ t, int b) {
    float w = q[b * 4 + 0], x = q[b * 4 + 1], y = q[b * 4 + 2], z = q[b * 4 + 3];
    float inv_n = 1.0f / sqrtf(w * w + x * x + y * y + z * z);
    w *= inv_n; x *= inv_n; y *= inv_n; z *= inv_n;
    float R00 = 1.f - 2.f * y * y - 2.f * z * z;
    float R01 = 2.f * x * y - 2.f * z * w;
    float R02 = 2.f * x * z + 2.f * y * w;
    float R10 = 2.f * x * y + 2.f * z * w;
    float R11 = 1.f - 2.f * x * x - 2.f * z * z;
    float R12 = 2.f * y * z - 2.f * x * w;
    float R20 = 2.f * x * z - 2.f * y * w;
    float R21 = 2.f * y * z + 2.f * x * w;
    float R22 = 1.f - 2.f * x * x - 2.f * y * y;
    float t0 = t[b * 3 + 0], t1 = t[b * 3 + 1], t2 = t[b * 3 + 2];
    Inv v;
    v.i00 = R00; v.i01 = R10; v.i02 = R20; v.it0 = -(R00 * t0 + R10 * t1 + R20 * t2);
    v.i10 = R01; v.i11 = R11; v.i12 = R21; v.it1 = -(R01 * t0 + R11 * t1 + R21 * t2);
    v.i20 = R02; v.i21 = R12; v.i22 = R22; v.it2 = -(R02 * t0 + R12 * t1 + R22 * t2);
    return v;
}

__device__ __forceinline__ void xf(const Inv& M, float px, float py, float pz,
                                   float& ox, float& oy, float& oz) {
    ox = fmaf(M.i00, px, fmaf(M.i01, py, fmaf(M.i02, pz, M.it0)));
    oy = fmaf(M.i10, px, fmaf(M.i11, py, fmaf(M.i12, pz, M.it1)));
    oz = fmaf(M.i20, px, fmaf(M.i21, py, fmaf(M.i22, pz, M.it2)));
}

// Barrier that drains ONLY lgkmcnt (LDS), NOT vmcnt — keeps global loads
// and stores in flight across the intra-block phase barriers.
__device__ __forceinline__ void bar_lgkm() {
    asm volatile("s_waitcnt lgkmcnt(0)\n\ts_barrier" ::: "memory");
}

using nat_f4 = __attribute__((ext_vector_type(4))) float;

// NT LOAD — the one measured win (R6, −5 us): bypasses L3 retention, turning
// the half-hit/half-miss read interleave (FETCH was pinned at exactly
// input/2 for all cached-read rounds) into a clean full HBM stream.
__device__ __forceinline__ float4 load_nt(const float4* p) {
    nat_f4 v = __builtin_nontemporal_load((const nat_f4*)p);
    float4 r; *(nat_f4*)&r = v; return r;
}

// Persistent pipelined structure:
//  - grid = 64 x 32 = 2048 blocks (8 blocks/CU exactly, no tail), 4 chunks
//    of 768 float4 (12 KB) per block;
//  - chunk i+1's 3 global loads issued at top of iter i, consumed after the
//    store phase (counted vmcnt, stores stay in flight);
//  - 2 lgkm-only barriers per iteration, single 12 KB LDS buffer (store-phase
//    ds_reads and restage ds_writes are same-thread same-address WAR pairs,
//    in-order per wave, no barrier between them);
//  - LDS compute-phase stride 12 words/lane -> conflict-free ds_read_b128;
//  - cached stores (policy measured neutral both regimes, R4/R7).
__global__ __launch_bounds__(256) void realign_fused_kernel(
        const float4* __restrict__ pcd,
        const float* __restrict__ T_mis,
        const float* __restrict__ q,
        const float* __restrict__ t,
        float* __restrict__ out_mat,
        float4* __restrict__ out_pcd,
        int f4_per_batch, int stride_f4, int n_iters) {
    __shared__ float4 smem[768];   // 12 KB
    const int b = blockIdx.y;
    const int tid = threadIdx.x;

    size_t base = (size_t)b * (size_t)f4_per_batch + (size_t)blockIdx.x * 768u;

    // Prologue: load + stage chunk 0 (b is wave-uniform -> make_inv scalarizes).
    float4 r0 = load_nt(&pcd[base + tid]);
    float4 r1 = load_nt(&pcd[base + 256 + tid]);
    float4 r2 = load_nt(&pcd[base + 512 + tid]);

    const Inv M = make_inv(q, t, b);

    // Fused tmat: batch_T_pred[b] = inv_T[b] @ T_mis[b] (once per batch).
    if (blockIdx.x == 0 && tid < 16) {
        const int i = tid >> 2;
        const int j = tid & 3;
        const float* Tb = T_mis + b * 16;
        float val;
        if (i < 3) {
            float a0, a1, a2, it;
            if (i == 0)      { a0 = M.i00; a1 = M.i01; a2 = M.i02; it = M.it0; }
            else if (i == 1) { a0 = M.i10; a1 = M.i11; a2 = M.i12; it = M.it1; }
            else             { a0 = M.i20; a1 = M.i21; a2 = M.i22; it = M.it2; }
            val = fmaf(a0, Tb[0 * 4 + j],
                  fmaf(a1, Tb[1 * 4 + j],
                  fmaf(a2, Tb[2 * 4 + j],
                       it * Tb[3 * 4 + j])));
        } else {
            val = Tb[3 * 4 + j];
        }
        out_mat[b * 16 + tid] = val;
    }

    smem[tid]       = r0;
    smem[256 + tid] = r1;
    smem[512 + tid] = r2;
    bar_lgkm();

    for (int it = 0; it < n_iters; ++it) {
        // Prefetch chunk it+1 into registers.
        float4 n0{}, n1{}, n2{};
        const bool has_next = (it + 1 < n_iters);
        if (has_next) {
            const size_t nb = base + (size_t)stride_f4;
            n0 = load_nt(&pcd[nb + tid]);
            n1 = load_nt(&pcd[nb + 256 + tid]);
            n2 = load_nt(&pcd[nb + 512 + tid]);
        }

        // Compute chunk `it` in place (each thread owns slots 3t..3t+2).
        float4 v0 = smem[3 * tid + 0];
        float4 v1 = smem[3 * tid + 1];
        float4 v2 = smem[3 * tid + 2];
        float4 o0, o1, o2;
        xf(M, v0.x, v0.y, v0.z, o0.x, o0.y, o0.z);
        xf(M, v0.w, v1.x, v1.y, o0.w, o1.x, o1.y);
        xf(M, v1.z, v1.w, v2.x, o1.z, o1.w, o2.x);
        xf(M, v2.y, v2.z, v2.w, o2.y, o2.z, o2.w);
        smem[3 * tid + 0] = o0;
        smem[3 * tid + 1] = o1;
        smem[3 * tid + 2] = o2;
        bar_lgkm();   // compute-writes visible to store-phase readers

        // Coalesced LDS -> global cached stores, then restage chunk it+1 into
        // the SAME slots (same thread, same address: in-order per wave, no
        // barrier needed between the read and the write).
        float4 s0 = smem[tid];
        float4 s1 = smem[256 + tid];
        float4 s2 = smem[512 + tid];
        out_pcd[base + tid]       = s0;
        out_pcd[base + 256 + tid] = s1;
        out_pcd[base + 512 + tid] = s2;
        if (has_next) {
            smem[tid]       = n0;
            smem[256 + tid] = n1;
            smem[512 + tid] = n2;
        }
        bar_lgkm();   // restage-writes visible to next iteration's compute

        base += (size_t)stride_f4;
    }
}

extern "C" void kernel_launch(void* const* d_in, const int* in_sizes, int n_in,
                              void* d_out, int out_size, void* d_ws, size_t ws_size,
                              hipStream_t stream) {
    const float* pcd   = (const float*)d_in[0];  // (B, N, 3)
    const float* T_mis = (const float*)d_in[1];  // (B, 4, 4)
    const float* q     = (const float*)d_in[2];  // (B, 4)
    const float* t     = (const float*)d_in[3];  // (B, 3)
    float* out = (float*)d_out;

    const int B = in_sizes[2] / 4;                            // 32
    const long long N = (long long)in_sizes[0] / (3LL * B);   // 262144
    const int f4_per_batch = (int)(3 * N / 4);                // 196608
    const int chunks = f4_per_batch / 768;                    // 256

    // 4 chunks per block -> 64 x 32 = 2048 blocks, persistent, no tail.
    int iters = 4;
    if (chunks % 4 != 0) iters = (chunks % 2 == 0) ? 2 : 1;
    const int blocks_x = chunks / iters;                      // 64
    const int stride_f4 = blocks_x * 768;

    // Output layout: [0, B*16) = batch_T_pred; then pcd_new (float4-aligned).
    dim3 grid(blocks_x, B);
    realign_fused_kernel<<<grid, 256, 0, stream>>>(
        (const float4*)pcd, T_mis, q, t,
        out, (float4*)(out + B * 16), f4_per_batch, stride_f4, iters);
}